// Round 1
// 360.067 us; speedup vs baseline: 1.8202x; 1.8202x over previous
//
#include <hip/hip_runtime.h>
#include <math.h>

#define B 4
#define C 64
#define NN 65536

typedef __attribute__((ext_vector_type(8))) short short8;
typedef __attribute__((ext_vector_type(4))) float f32x4;

__device__ inline float bf2f(short s) {
  union { unsigned u; float f; } v; v.u = ((unsigned)(unsigned short)s) << 16; return v.f;
}
__device__ inline short f2bf(float f) {
  union { float f; unsigned u; } v; v.f = f;
  unsigned r = v.u + 0x7FFFu + ((v.u >> 16) & 1u);  // RNE
  return (short)(r >> 16);
}

// ---------------------------------------------------------------------------
// P1: pack w_qkv (first 128 rows) and w_m1 into MFMA A-frag order; zero gram2.
// A-frag (16x16x32): lane l holds A[m=l&15][k=(l>>4)*8+j], j=0..7.
__global__ void k_prep1(const float* __restrict__ wqkv, const float* __restrict__ wm1,
    short* __restrict__ apk, short* __restrict__ apm, float* __restrict__ gram2) {
  for (int idx = blockIdx.x * 256 + threadIdx.x; idx < 20480; idx += 16384) {
    if (idx < 8192) {
      const int j = idx & 7, lane = (idx >> 3) & 63, mt = (idx >> 9) & 7, cc = idx >> 12;
      const int o = mt * 16 + (lane & 15), c = cc * 32 + (lane >> 4) * 8 + j;
      apk[idx] = f2bf(wqkv[o * 64 + c]);
    } else if (idx < 12288) {
      const int k = idx - 8192;
      const int j = k & 7, lane = (k >> 3) & 63, mt = (k >> 9) & 3, cc = k >> 11;
      const int o = mt * 16 + (lane & 15), c = cc * 32 + (lane >> 4) * 8 + j;
      apm[k] = f2bf(wm1[o * 64 + c]);
    } else {
      gram2[idx - 12288] = 0.f;
    }
  }
}

// P2: pack w2 (OIHW 64x64x5x5) -> A-frag order [t][cc][mt][lane][j].
// Launched AFTER k_gram (its buffer aliases the dead qk region).
__global__ void k_prep2(const float* __restrict__ w2, short* __restrict__ apw2) {
  for (int idx = blockIdx.x * 256 + threadIdx.x; idx < 25 * 2 * 4 * 64 * 8; idx += 16384) {
    const int j = idx & 7, lane = (idx >> 3) & 63, mt = (idx >> 9) & 3,
              cc = (idx >> 11) & 1, t = idx >> 12;
    const int o = mt * 16 + (lane & 15);
    const int c = cc * 32 + (lane >> 4) * 8 + j;
    apw2[idx] = f2bf(w2[((size_t)o * 64 + c) * 25 + t]);
  }
}

// ---------------------------------------------------------------------------
// XT: x[b,c,n] fp32 -> x_t[b,n,64] bf16 (channel-innermost) via LDS transpose.
__global__ __launch_bounds__(256) void k_xt(const float* __restrict__ x,
    short* __restrict__ x_t) {
  __shared__ short lds[256 * 72];
  const int b = blockIdx.x >> 8, n0 = (blockIdx.x & 255) << 8;
  const int t = threadIdx.x;
#pragma unroll 4
  for (int c = 0; c < 64; ++c)
    lds[t * 72 + c] = f2bf(x[((size_t)(b * 64 + c)) * NN + n0 + t]);
  __syncthreads();
  short* dst = x_t + ((size_t)(b * NN + n0)) * 64;
#pragma unroll
  for (int it = 0; it < 8; ++it) {
    const int idx = it * 256 + t;
    const int nl = idx >> 3, cb = idx & 7;
    *(short8*)(dst + (size_t)nl * 64 + cb * 8) = *(const short8*)(lds + nl * 72 + cb * 8);
  }
}

// ---------------------------------------------------------------------------
// K1: qk 1x1 conv as MFMA GEMM: qk[b,o<128,n] = wqkv.x + b. B-frag straight
// from x_t (one short8 global load per k-chunk; no LDS).
__global__ __launch_bounds__(256, 4) void k_qk1x1(const short* __restrict__ x_t,
    const short* __restrict__ apk, const float* __restrict__ bias,
    short* __restrict__ qk) {
  const int b = blockIdx.x >> 10, ntile = blockIdx.x & 1023;
  const int wave = threadIdx.x >> 6, lane = threadIdx.x & 63;
  const int quad = lane >> 4, l15 = lane & 15;
  const int n = ntile * 64 + wave * 16 + l15;
  f32x4 acc[8];
#pragma unroll
  for (int mt = 0; mt < 8; ++mt) acc[mt] = (f32x4){0.f, 0.f, 0.f, 0.f};
#pragma unroll
  for (int cc = 0; cc < 2; ++cc) {
    const short8 bf = *(const short8*)(x_t + ((size_t)(b * NN + n)) * 64 + cc * 32 + quad * 8);
#pragma unroll
    for (int mt = 0; mt < 8; ++mt) {
      const short8 af = *(const short8*)(apk + ((cc * 8 + mt) * 64 + lane) * 8);
      acc[mt] = __builtin_amdgcn_mfma_f32_16x16x32_bf16(af, bf, acc[mt], 0, 0, 0);
    }
  }
#pragma unroll
  for (int mt = 0; mt < 8; ++mt)
#pragma unroll
    for (int reg = 0; reg < 4; ++reg) {
      const int o = mt * 16 + quad * 4 + reg;
      qk[((size_t)(b * 128 + o)) * NN + n] = f2bf(acc[mt][reg] + bias[o]);
    }
}

// ---------------------------------------------------------------------------
// K2: FUSED depthwise-3x3 + Gram, latency-optimized.
// Each wave owns one full image row (wave-uniform y): per s-step a lane
// computes 8 dw outputs of its channel (ch = l15 -> 8 q-rows / 8 k-rows of
// head h) from ONE aligned short8 load + 2 predicated edge scalars per tap
// row, then mfma(frag, frag) accumulates S.S^T. 4-wave LDS reduction before
// the global atomics (524K atomics total instead of 2M).
__global__ __launch_bounds__(256, 4) void k_gram(const short* __restrict__ qk,
    const float* __restrict__ wdw, const float* __restrict__ bdw,
    float* __restrict__ gram2) {
  __shared__ float red[4][256];
  const int bh = blockIdx.x >> 6, chunk = blockIdx.x & 63;
  const int b = bh >> 3, h = bh & 7;
  const int wave = threadIdx.x >> 6, lane = threadIdx.x & 63;
  const int quad = lane >> 4, l15 = lane & 15;
  const int ch = (l15 < 8) ? (h * 8 + l15) : (64 + h * 8 + (l15 - 8));
  const short* plane = qk + ((size_t)(b * 128 + ch)) * NN;
  float wreg[9];
#pragma unroll
  for (int i = 0; i < 9; ++i) wreg[i] = wdw[ch * 9 + i];
  const float bias = bdw[ch];
  const int row = chunk * 4 + wave;          // wave-uniform output row 0..255
  const short* prow = plane + row * 256;
  f32x4 acc = {0.f, 0.f, 0.f, 0.f};
  for (int s = 0; s < 8; ++s) {
    const int px0 = s * 32 + quad * 8;       // 8-aligned -> 16B-aligned loads
    float a[8];
#pragma unroll
    for (int j = 0; j < 8; ++j) a[j] = bias;
#pragma unroll
    for (int dy = 0; dy < 3; ++dy) {
      if (dy == 0 && row == 0) continue;     // wave-uniform branches
      if (dy == 2 && row == 255) continue;
      const short* pr = prow + (dy - 1) * 256 + px0;
      const short8 mid = *(const short8*)pr;
      float m[10];
      m[0] = 0.f;
      if (px0 > 0) m[0] = bf2f(pr[-1]);      // predicated: no OOB speculation
      m[9] = 0.f;
      if (px0 < 248) m[9] = bf2f(pr[8]);
#pragma unroll
      for (int k = 0; k < 8; ++k) m[k + 1] = bf2f(mid[k]);
      const float w0 = wreg[dy * 3], w1 = wreg[dy * 3 + 1], w2 = wreg[dy * 3 + 2];
#pragma unroll
      for (int j = 0; j < 8; ++j)
        a[j] = fmaf(w2, m[j + 2], fmaf(w1, m[j + 1], fmaf(w0, m[j], a[j])));
    }
    short8 frag;
#pragma unroll
    for (int j = 0; j < 8; ++j) frag[j] = f2bf(a[j]);
    acc = __builtin_amdgcn_mfma_f32_16x16x32_bf16(frag, frag, acc, 0, 0, 0);
  }
#pragma unroll
  for (int reg = 0; reg < 4; ++reg)
    red[wave][(quad * 4 + reg) * 16 + l15] = acc[reg];
  __syncthreads();
  {
    const int e = threadIdx.x;
    const float s4 = red[0][e] + red[1][e] + red[2][e] + red[3][e];
    atomicAdd(&gram2[bh * 256 + e], s4);
  }
}

// ---------------------------------------------------------------------------
// K3: m1 1x1 conv + BN as MFMA GEMM -> y_t[b,n,64] bf16 via LDS repack.
__global__ __launch_bounds__(256, 4) void k_m1_bn(const short* __restrict__ x_t,
    const short* __restrict__ apm, const float* __restrict__ gamma,
    const float* __restrict__ beta, const float* __restrict__ mean,
    const float* __restrict__ var, short* __restrict__ y_t) {
  __shared__ short lds[64 * 72];
  const int b = blockIdx.x >> 10, ntile = blockIdx.x & 1023;
  const int wave = threadIdx.x >> 6, lane = threadIdx.x & 63;
  const int quad = lane >> 4, l15 = lane & 15;
  const int n = ntile * 64 + wave * 16 + l15;
  f32x4 acc[4];
#pragma unroll
  for (int mt = 0; mt < 4; ++mt) acc[mt] = (f32x4){0.f, 0.f, 0.f, 0.f};
#pragma unroll
  for (int cc = 0; cc < 2; ++cc) {
    const short8 bf = *(const short8*)(x_t + ((size_t)(b * NN + n)) * 64 + cc * 32 + quad * 8);
#pragma unroll
    for (int mt = 0; mt < 4; ++mt) {
      const short8 af = *(const short8*)(apm + ((cc * 4 + mt) * 64 + lane) * 8);
      acc[mt] = __builtin_amdgcn_mfma_f32_16x16x32_bf16(af, bf, acc[mt], 0, 0, 0);
    }
  }
#pragma unroll
  for (int mt = 0; mt < 4; ++mt)
#pragma unroll
    for (int reg = 0; reg < 4; ++reg) {
      const int o = mt * 16 + quad * 4 + reg;
      const float sc = gamma[o] * rsqrtf(var[o] + 1e-5f);
      lds[(wave * 16 + l15) * 72 + o] = f2bf((acc[mt][reg] - mean[o]) * sc + beta[o]);
    }
  __syncthreads();
  short* dst = y_t + ((size_t)(b * NN + ntile * 64)) * 64;
#pragma unroll
  for (int it = 0; it < 2; ++it) {
    const int idx = it * 256 + threadIdx.x;
    const int lcol = idx >> 3, cb = idx & 7;
    *(short8*)(dst + (size_t)lcol * 64 + cb * 8) = *(const short8*)(lds + lcol * 72 + cb * 8);
  }
}

// ---------------------------------------------------------------------------
// K4: conv5x5 implicit-GEMM MFMA; epilogue v = x*(1+sigmoid(.)) written
// channel-innermost v_t[b,n,64] via LDS repack (reuses the staging LDS).
__global__ __launch_bounds__(256, 2) void k_conv5(const short* __restrict__ y_t,
    const short* __restrict__ apw2, const short* __restrict__ x_t,
    short* __restrict__ v_t) {
  __shared__ short slds[8 * 68 * 40];  // staging: [row8][col68][ch32+pad] = 43.5KB
  const int b = blockIdx.x >> 8;
  const int rg = (blockIdx.x >> 2) & 63, cg = blockIdx.x & 3;
  const int r0 = rg * 4, x0 = cg * 64;
  const int wave = threadIdx.x >> 6, lane = threadIdx.x & 63;
  const int quad = lane >> 4, l15 = lane & 15;
  f32x4 acc[4][4];
#pragma unroll
  for (int mt = 0; mt < 4; ++mt)
#pragma unroll
    for (int nt = 0; nt < 4; ++nt) acc[mt][nt] = (f32x4){0.f, 0.f, 0.f, 0.f};
  for (int cc = 0; cc < 2; ++cc) {
    if (cc) __syncthreads();
    for (int idx = threadIdx.x; idx < 8 * 68 * 4; idx += 256) {
      const int rr = idx / 272, rem = idx - rr * 272;
      const int col = rem >> 2, cb = rem & 3;
      const int gr = r0 - 2 + rr, gc = x0 - 2 + col;
      short8 val = {0, 0, 0, 0, 0, 0, 0, 0};
      if (gr >= 0 && gr < 256 && gc >= 0 && gc < 256)
        val = *(const short8*)(y_t + ((size_t)(b * NN + gr * 256 + gc)) * 64 + cc * 32 + cb * 8);
      *(short8*)(slds + (rr * 68 + col) * 40 + cb * 8) = val;
    }
    __syncthreads();
    for (int t = 0; t < 25; ++t) {
      const int dy = t / 5 - 2, dx = t % 5 - 2;
      short8 a[4];
#pragma unroll
      for (int mt = 0; mt < 4; ++mt)
        a[mt] = *(const short8*)(apw2 + (((t * 2 + cc) * 4 + mt) * 64 + lane) * 8);
      const int rr = wave + 2 + dy;
#pragma unroll
      for (int nt = 0; nt < 4; ++nt) {
        const int colL = nt * 16 + l15 + 2 + dx;
        const short8 bf = *(const short8*)(slds + (rr * 68 + colL) * 40 + quad * 8);
#pragma unroll
        for (int mt = 0; mt < 4; ++mt)
          acc[mt][nt] = __builtin_amdgcn_mfma_f32_16x16x32_bf16(a[mt], bf, acc[mt][nt], 0, 0, 0);
      }
    }
  }
  __syncthreads();  // done reading staging; reuse slds as [row4][col64][72]
  const int row = r0 + wave;
#pragma unroll
  for (int mt = 0; mt < 4; ++mt)
#pragma unroll
    for (int nt = 0; nt < 4; ++nt)
#pragma unroll
      for (int reg = 0; reg < 4; ++reg) {
        const int o = mt * 16 + quad * 4 + reg;
        const int lcol = nt * 16 + l15;
        const float xv = bf2f(x_t[((size_t)(b * NN + row * 256 + x0 + lcol)) * 64 + o]);
        const float sg = 1.f / (1.f + __expf(-acc[mt][nt][reg]));
        slds[(wave * 64 + lcol) * 72 + o] = f2bf(xv * (1.f + sg));
      }
  __syncthreads();
#pragma unroll
  for (int it = 0; it < 8; ++it) {
    const int idx = it * 256 + threadIdx.x;
    const int cb = idx & 7, lcol = (idx >> 3) & 63, rr = idx >> 9;
    *(short8*)(v_t + ((size_t)(b * NN + (r0 + rr) * 256 + x0 + lcol)) * 64 + cb * 8) =
        *(const short8*)(slds + (rr * 64 + lcol) * 72 + cb * 8);
  }
}

// ---------------------------------------------------------------------------
// K5: softmax from gram2, fold wproj, emit E directly in bf16 A-frag order:
// Epack[b][cc][mt][lane][j] with A[m=o][k=cv].
__global__ __launch_bounds__(256) void k_attn_e(const float* __restrict__ gram2,
    const float* __restrict__ temp, const float* __restrict__ wproj,
    short* __restrict__ Epack) {
  __shared__ float attn[2048];
  const int t = threadIdx.x;
  {
    const int b = t >> 6, h = (t >> 3) & 7, c = t & 7;
    const float* g = gram2 + (b * 8 + h) * 256;
    const float qn = fmaxf(sqrtf(g[c * 16 + c]), 1e-12f);
    const float tp = temp[h];
    float row[8];
    float mx = -1e30f;
#pragma unroll
    for (int d = 0; d < 8; ++d) {
      const float kn = fmaxf(sqrtf(g[(8 + d) * 16 + (8 + d)]), 1e-12f);
      row[d] = g[c * 16 + 8 + d] / (qn * kn) * tp;
      mx = fmaxf(mx, row[d]);
    }
    float s = 0.f;
#pragma unroll
    for (int d = 0; d < 8; ++d) { row[d] = __expf(row[d] - mx); s += row[d]; }
    const float inv = 1.f / s;
#pragma unroll
    for (int d = 0; d < 8; ++d) attn[t * 8 + d] = row[d] * inv;
  }
  __syncthreads();
  for (int idx = t; idx < 16384; idx += 256) {
    const int j = idx & 7, lane = (idx >> 3) & 63, mt = (idx >> 9) & 3,
              cc = (idx >> 11) & 1, b = idx >> 12;
    const int o = mt * 16 + (lane & 15);
    const int cv = cc * 32 + (lane >> 4) * 8 + j;
    const int h = cv >> 3, d = cv & 7;
    float a = 0.f;
#pragma unroll
    for (int c2 = 0; c2 < 8; ++c2)
      a += wproj[o * 64 + h * 8 + c2] * attn[((b * 8 + h) * 8 + c2) * 8 + d];
    Epack[idx] = f2bf(a);
  }
}

// ---------------------------------------------------------------------------
// K6: out[b,o,n] = bproj[o] + E[b].v_t  as per-batch MFMA GEMM, fp32 stores.
__global__ __launch_bounds__(256, 4) void k_out(const short* __restrict__ v_t,
    const short* __restrict__ Epack, const float* __restrict__ bproj,
    float* __restrict__ out) {
  const int b = blockIdx.x >> 10, ntile = blockIdx.x & 1023;
  const int wave = threadIdx.x >> 6, lane = threadIdx.x & 63;
  const int quad = lane >> 4, l15 = lane & 15;
  const int n = ntile * 64 + wave * 16 + l15;
  f32x4 acc[4];
#pragma unroll
  for (int mt = 0; mt < 4; ++mt) acc[mt] = (f32x4){0.f, 0.f, 0.f, 0.f};
#pragma unroll
  for (int cc = 0; cc < 2; ++cc) {
    const short8 bf = *(const short8*)(v_t + ((size_t)(b * NN + n)) * 64 + cc * 32 + quad * 8);
#pragma unroll
    for (int mt = 0; mt < 4; ++mt) {
      const short8 af = *(const short8*)(Epack + (((b * 2 + cc) * 4 + mt) * 64 + lane) * 8);
      acc[mt] = __builtin_amdgcn_mfma_f32_16x16x32_bf16(af, bf, acc[mt], 0, 0, 0);
    }
  }
#pragma unroll
  for (int mt = 0; mt < 4; ++mt)
#pragma unroll
    for (int reg = 0; reg < 4; ++reg) {
      const int o = mt * 16 + quad * 4 + reg;
      out[((size_t)(b * 64 + o)) * NN + n] = acc[mt][reg] + bproj[o];
    }
}

// ---------------------------------------------------------------------------
// Workspace (byte offsets), total 134307840 <= proven ws capacity:
//  [0,   64M)  qk bf16 [b][128][N]  -> after k_gram: v_t [0,32M), apw2 @32M
//  [64M, 96M)  x_t bf16 [b][n][64]
//  [96M,128M)  y_t bf16 [b][n][64]
//  [128M, ..)  gram2 32KB | apk 16KB | apm 8KB | Epack 32KB
extern "C" void kernel_launch(void* const* d_in, const int* in_sizes, int n_in,
                              void* d_out, int out_size, void* d_ws, size_t ws_size,
                              hipStream_t stream) {
  const float* x     = (const float*)d_in[0];
  const float* wqkv  = (const float*)d_in[1];
  const float* bqkv  = (const float*)d_in[2];
  const float* wdw   = (const float*)d_in[3];
  const float* bdw   = (const float*)d_in[4];
  const float* wproj = (const float*)d_in[5];
  const float* bproj = (const float*)d_in[6];
  const float* temp  = (const float*)d_in[7];
  const float* wm1   = (const float*)d_in[8];
  const float* gamma = (const float*)d_in[9];
  const float* beta  = (const float*)d_in[10];
  const float* mean  = (const float*)d_in[11];
  const float* var   = (const float*)d_in[12];
  const float* wm2   = (const float*)d_in[13];

  char* wsb = (char*)d_ws;
  short* qk    = (short*)(wsb);
  short* v_t   = (short*)(wsb);                       // aliases qk (after k_gram)
  short* apw2  = (short*)(wsb + 33554432);            // aliases qk tail (after k_gram)
  short* x_t   = (short*)(wsb + 67108864);
  short* y_t   = (short*)(wsb + 100663296);
  float* gram2 = (float*)(wsb + 134217728);
  short* apk   = (short*)(wsb + 134217728 + 32768);
  short* apm   = (short*)(wsb + 134217728 + 49152);
  short* Epack = (short*)(wsb + 134217728 + 57344);
  float* out   = (float*)d_out;

  k_prep1<<<dim3(64), dim3(256), 0, stream>>>(wqkv, wm1, apk, apm, gram2);
  k_xt<<<dim3(1024), dim3(256), 0, stream>>>(x, x_t);
  k_qk1x1<<<dim3(4096), dim3(256), 0, stream>>>(x_t, apk, bqkv, qk);
  k_gram<<<dim3(2048), dim3(256), 0, stream>>>(qk, wdw, bdw, gram2);
  k_prep2<<<dim3(64), dim3(256), 0, stream>>>(wm2, apw2);
  k_m1_bn<<<dim3(4096), dim3(256), 0, stream>>>(x_t, apm, gamma, beta, mean, var, y_t);
  k_conv5<<<dim3(1024), dim3(256), 0, stream>>>(y_t, apw2, x_t, v_t);
  k_attn_e<<<dim3(1), dim3(256), 0, stream>>>(gram2, temp, wproj, Epack);
  k_out<<<dim3(4096), dim3(256), 0, stream>>>(v_t, Epack, bproj, out);
}